// Round 1
// baseline (678.859 us; speedup 1.0000x reference)
//
#include <hip/hip_runtime.h>
#include <math.h>

// Problem constants (from setup_inputs)
#define N_NODES  100000
#define N_EDGES  2000000
#define F_IN     32
#define HID      40
#define N_GRAPHS 512
#define SCAN_BS  512
#define NB_SCAN  ((N_NODES + SCAN_BS - 1) / SCAN_BS)   // 196

// ---------------- CSR build ----------------

__global__ void k_degree(const int* __restrict__ dst, int* __restrict__ deg) {
    int e = blockIdx.x * blockDim.x + threadIdx.x;
    if (e < N_EDGES) atomicAdd(&deg[dst[e]], 1);
}

// in-place exclusive scan stage 1: off[] holds degrees on entry, local-exclusive on exit
__global__ void k_scan1(int* __restrict__ off, int* __restrict__ partial) {
    __shared__ int lds[SCAN_BS];
    int i = blockIdx.x * SCAN_BS + threadIdx.x;
    int d = (i < N_NODES) ? off[i] : 0;
    lds[threadIdx.x] = d;
    __syncthreads();
    for (int ofs = 1; ofs < SCAN_BS; ofs <<= 1) {
        int v = (threadIdx.x >= (unsigned)ofs) ? lds[threadIdx.x - ofs] : 0;
        __syncthreads();
        lds[threadIdx.x] += v;
        __syncthreads();
    }
    int incl = lds[threadIdx.x];
    if (i < N_NODES) off[i] = incl - d;               // exclusive within block
    if (threadIdx.x == SCAN_BS - 1) partial[blockIdx.x] = incl;  // block total
}

__global__ void k_scan_mid(int* __restrict__ partial, int nb) {
    __shared__ int lds[256];
    int d = (threadIdx.x < (unsigned)nb) ? partial[threadIdx.x] : 0;
    lds[threadIdx.x] = d;
    __syncthreads();
    for (int ofs = 1; ofs < 256; ofs <<= 1) {
        int v = (threadIdx.x >= (unsigned)ofs) ? lds[threadIdx.x - ofs] : 0;
        __syncthreads();
        lds[threadIdx.x] += v;
        __syncthreads();
    }
    if (threadIdx.x < (unsigned)nb) partial[threadIdx.x] = lds[threadIdx.x] - d; // exclusive
}

__global__ void k_scan_add(int* __restrict__ off, int* __restrict__ cur,
                           const int* __restrict__ partial) {
    int i = blockIdx.x * SCAN_BS + threadIdx.x;
    if (i < N_NODES) {
        int v = off[i] + partial[blockIdx.x];
        off[i] = v;
        cur[i] = v;
    }
    if (blockIdx.x == 0 && threadIdx.x == 0) off[N_NODES] = N_EDGES;
}

__global__ void k_fill(const int* __restrict__ src, const int* __restrict__ dst,
                       int* __restrict__ cur, int* __restrict__ csr) {
    int e = blockIdx.x * blockDim.x + threadIdx.x;
    if (e < N_EDGES) {
        int p = atomicAdd(&cur[dst[e]], 1);
        csr[p] = src[e];
    }
}

// ---------------- per-layer aggregation: agg[n] = sum_{j in-neigh(n)} feat[j] ----------------
// R4 = float4s per row (8 for F=32, 10 for H=40). Thread = (node, f4).

template<int R4>
__global__ void k_aggregate(const float4* __restrict__ feat, const int* __restrict__ off,
                            const int* __restrict__ csr, float4* __restrict__ agg) {
    int t = blockIdx.x * blockDim.x + threadIdx.x;
    if (t >= N_NODES * R4) return;
    int node = t / R4;
    int f4   = t - node * R4;
    int s = off[node], e = off[node + 1];
    float4 acc = make_float4(0.f, 0.f, 0.f, 0.f);
    const float4* fp = feat + f4;
    for (int k = s; k < e; ++k) {
        int j = csr[k];
        float4 v = fp[(size_t)j * R4];
        acc.x += v.x; acc.y += v.y; acc.z += v.z; acc.w += v.w;
    }
    agg[(size_t)node * R4 + f4] = acc;
}

// ---------------- transform: h = bn(act(agg@w_rel + x@w_root + b)) ----------------
// thread = node; weights staged in LDS, read as uniform-broadcast float4s.

template<int F, bool RELU>
__global__ __launch_bounds__(256)
void k_transform(const float* __restrict__ feat_in, const float* __restrict__ agg,
                 const float* __restrict__ w_rel, const float* __restrict__ w_root,
                 const float* __restrict__ bias,
                 const float* __restrict__ bn_g, const float* __restrict__ bn_b,
                 const float* __restrict__ bn_m, const float* __restrict__ bn_v,
                 float* __restrict__ h_out) {
    __shared__ __align__(16) float wl[F * HID];
    __shared__ __align__(16) float wr[F * HID];
    __shared__ __align__(16) float sb[HID];
    __shared__ __align__(16) float tb[HID];
    __shared__ __align__(16) float bb[HID];
    for (int i = threadIdx.x; i < F * HID; i += blockDim.x) {
        wl[i] = w_rel[i];
        wr[i] = w_root[i];
    }
    if (threadIdx.x < HID) {
        float s = bn_g[threadIdx.x] * rsqrtf(bn_v[threadIdx.x] + 1e-5f);
        sb[threadIdx.x] = s;
        tb[threadIdx.x] = bn_b[threadIdx.x] - bn_m[threadIdx.x] * s;
        bb[threadIdx.x] = bias[threadIdx.x];
    }
    __syncthreads();
    int node = blockIdx.x * blockDim.x + threadIdx.x;
    if (node >= N_NODES) return;

    float a[F], xr[F];
    const float4* af = (const float4*)(agg     + (size_t)node * F);
    const float4* xf = (const float4*)(feat_in + (size_t)node * F);
#pragma unroll
    for (int i = 0; i < F / 4; ++i) {
        ((float4*)a)[i]  = af[i];
        ((float4*)xr)[i] = xf[i];
    }

    float4* out4 = (float4*)(h_out + (size_t)node * HID);
    for (int j4 = 0; j4 < HID / 4; ++j4) {          // not unrolled: keep I$ small
        float4 acc = ((const float4*)bb)[j4];
        const float4* wl4 = ((const float4*)wl) + j4;
        const float4* wr4 = ((const float4*)wr) + j4;
#pragma unroll
        for (int i = 0; i < F; ++i) {
            float4 w = wl4[i * (HID / 4)];
            acc.x += a[i] * w.x; acc.y += a[i] * w.y;
            acc.z += a[i] * w.z; acc.w += a[i] * w.w;
        }
#pragma unroll
        for (int i = 0; i < F; ++i) {
            float4 w = wr4[i * (HID / 4)];
            acc.x += xr[i] * w.x; acc.y += xr[i] * w.y;
            acc.z += xr[i] * w.z; acc.w += xr[i] * w.w;
        }
        if (RELU) {
            acc.x = fmaxf(acc.x, 0.f); acc.y = fmaxf(acc.y, 0.f);
            acc.z = fmaxf(acc.z, 0.f); acc.w = fmaxf(acc.w, 0.f);
        }
        float4 s = ((const float4*)sb)[j4];
        float4 t = ((const float4*)tb)[j4];
        acc.x = s.x * acc.x + t.x; acc.y = s.y * acc.y + t.y;
        acc.z = s.z * acc.z + t.z; acc.w = s.w * acc.w + t.w;
        out4[j4] = acc;
    }
}

// ---------------- pool + head: one block per graph ----------------

__global__ void k_pool_head(const float* __restrict__ h, const int* __restrict__ batch,
                            const float* __restrict__ wl1, const float* __restrict__ bl1,
                            const float* __restrict__ wl2, const float* __restrict__ bl2,
                            float* __restrict__ out) {
    int g = blockIdx.x;
    // lower_bound(batch, g) and lower_bound(batch, g+1); batch sorted ascending
    int lo = 0, hi = N_NODES;
    while (lo < hi) { int mid = (lo + hi) >> 1; if (batch[mid] < g) lo = mid + 1; else hi = mid; }
    int start = lo;
    hi = N_NODES;
    while (lo < hi) { int mid = (lo + hi) >> 1; if (batch[mid] < g + 1) lo = mid + 1; else hi = mid; }
    int end = lo;

    int j = threadIdx.x;
    __shared__ float gm[HID];
    __shared__ float l1[10];
    if (j < HID) {
        float m = -INFINITY;
        for (int r = start; r < end; ++r) m = fmaxf(m, h[(size_t)r * HID + j]);
        if (!isfinite(m)) m = 0.f;   // empty-graph guard (matches jnp.where(isfinite))
        gm[j] = m;
    }
    __syncthreads();
    if (j < 10) {
        float acc = bl1[j];
#pragma unroll
        for (int i = 0; i < HID; ++i) acc += gm[i] * wl1[i * 10 + j];
        l1[j] = fmaxf(acc, 0.f);
    }
    __syncthreads();
    if (j == 0) {
        float acc = bl2[0];
#pragma unroll
        for (int i = 0; i < 10; ++i) acc += l1[i] * wl2[i];
        out[g] = 1.f / (1.f + expf(-acc));
    }
}

// ---------------- launch ----------------

extern "C" void kernel_launch(void* const* d_in, const int* in_sizes, int n_in,
                              void* d_out, int out_size, void* d_ws, size_t ws_size,
                              hipStream_t stream) {
    const float* x       = (const float*)d_in[0];
    const int*   ei      = (const int*)d_in[1];
    const int*   src     = ei;              // edge_index[0]
    const int*   dst     = ei + N_EDGES;    // edge_index[1]
    const int*   batch   = (const int*)d_in[3];
    const float* w1_rel  = (const float*)d_in[5];
    const float* w1_root = (const float*)d_in[6];
    const float* b1      = (const float*)d_in[7];
    const float* w2_rel  = (const float*)d_in[8];
    const float* w2_root = (const float*)d_in[9];
    const float* b2      = (const float*)d_in[10];
    const float* w3_rel  = (const float*)d_in[11];
    const float* w3_root = (const float*)d_in[12];
    const float* b3      = (const float*)d_in[13];
    const float* bn1_g = (const float*)d_in[14], *bn1_b = (const float*)d_in[15];
    const float* bn1_m = (const float*)d_in[16], *bn1_v = (const float*)d_in[17];
    const float* bn2_g = (const float*)d_in[18], *bn2_b = (const float*)d_in[19];
    const float* bn2_m = (const float*)d_in[20], *bn2_v = (const float*)d_in[21];
    const float* bn3_g = (const float*)d_in[22], *bn3_b = (const float*)d_in[23];
    const float* bn3_m = (const float*)d_in[24], *bn3_v = (const float*)d_in[25];
    const float* wl1 = (const float*)d_in[26], *bl1 = (const float*)d_in[27];
    const float* wl2 = (const float*)d_in[28], *bl2 = (const float*)d_in[29];
    float* out = (float*)d_out;

    // workspace layout (~57 MB total)
    char* ws = (char*)d_ws;
    size_t o = 0;
    auto take = [&](size_t bytes) -> void* {
        void* p = ws + o;
        o = (o + bytes + 255) & ~(size_t)255;
        return p;
    };
    int*   off     = (int*)take((N_NODES + 1) * sizeof(int));
    int*   cur     = (int*)take(N_NODES * sizeof(int));
    int*   partial = (int*)take(1024 * sizeof(int));
    int*   csr     = (int*)take((size_t)N_EDGES * sizeof(int));
    float* agg     = (float*)take((size_t)N_NODES * HID * sizeof(float));
    float* hA      = (float*)take((size_t)N_NODES * HID * sizeof(float));
    float* hB      = (float*)take((size_t)N_NODES * HID * sizeof(float));

    const int TB = 256;
    const int edge_blocks = (N_EDGES + TB - 1) / TB;
    const int node_blocks = (N_NODES + TB - 1) / TB;

    // CSR build (once per call; shared by all 3 layers)
    hipMemsetAsync(off, 0, (N_NODES + 1) * sizeof(int), stream);
    k_degree<<<edge_blocks, TB, 0, stream>>>(dst, off);
    k_scan1<<<NB_SCAN, SCAN_BS, 0, stream>>>(off, partial);
    k_scan_mid<<<1, 256, 0, stream>>>(partial, NB_SCAN);
    k_scan_add<<<NB_SCAN, SCAN_BS, 0, stream>>>(off, cur, partial);
    k_fill<<<edge_blocks, TB, 0, stream>>>(src, dst, cur, csr);

    // layer 1: F=32 -> 40, relu then bn
    k_aggregate<8><<<(N_NODES * 8 + TB - 1) / TB, TB, 0, stream>>>(
        (const float4*)x, off, csr, (float4*)agg);
    k_transform<32, true><<<node_blocks, TB, 0, stream>>>(
        x, agg, w1_rel, w1_root, b1, bn1_g, bn1_b, bn1_m, bn1_v, hA);

    // layer 2: 40 -> 40, relu then bn
    k_aggregate<10><<<(N_NODES * 10 + TB - 1) / TB, TB, 0, stream>>>(
        (const float4*)hA, off, csr, (float4*)agg);
    k_transform<40, true><<<node_blocks, TB, 0, stream>>>(
        hA, agg, w2_rel, w2_root, b2, bn2_g, bn2_b, bn2_m, bn2_v, hB);

    // layer 3: 40 -> 40, bn only (no relu)
    k_aggregate<10><<<(N_NODES * 10 + TB - 1) / TB, TB, 0, stream>>>(
        (const float4*)hB, off, csr, (float4*)agg);
    k_transform<40, false><<<node_blocks, TB, 0, stream>>>(
        hB, agg, w3_rel, w3_root, b3, bn3_g, bn3_b, bn3_m, bn3_v, hA);

    // global max pool + MLP head + sigmoid
    k_pool_head<<<N_GRAPHS, 64, 0, stream>>>(hA, batch, wl1, bl1, wl2, bl2, out);
}